// Round 1
// baseline (4478.303 us; speedup 1.0000x reference)
//
#include <hip/hip_runtime.h>
#include <hip/hip_bf16.h>
#include <hip/hip_cooperative_groups.h>

namespace cg = cooperative_groups;

#define S_ 48
#define D_ 128
#define H_ 512
#define L_ 256
#define V_ 6000
#define SD_ 6144      // S*D
#define M3_ 3072      // 6*H permuted gate rows per tree

typedef __attribute__((ext_vector_type(8))) short short8;
typedef __attribute__((ext_vector_type(4))) float f32x4;
typedef __hip_bfloat16 bf16;

__device__ __forceinline__ float sigm(float x) { return 1.0f / (1.0f + __expf(-x)); }
__device__ __forceinline__ f32x4 zero4() { f32x4 z; z[0]=0.f; z[1]=0.f; z[2]=0.f; z[3]=0.f; return z; }

// ---------------------------------------------------------------------------
// Prep: build permuted bf16 weights. Row p (within a tree): j=p/6, t6=p%6,
// branch = (t6<3 ? child : sibling), gate g=t6%3 in (r,z,n) order.
// bias_gi = bih + (g<2 ? bhh : 0)   (folded into the gi GEMM, bias-on-M)
// bias_ghn = (g==2 ? bhh : 0)       (added to gh_n in the recurrence epilogue)
// ---------------------------------------------------------------------------
struct PrepArgs {
  const float* wih[4]; const float* whh[4];
  const float* bih[4]; const float* bhh[4];
};

__global__ __launch_bounds__(64) void k_prep_w(PrepArgs pa, bf16* __restrict__ wihp,
                                               bf16* __restrict__ whhp,
                                               float* __restrict__ bgi,
                                               float* __restrict__ bghn) {
  const int R = blockIdx.x;          // 0..6143 (tree-major)
  const int tree = R / M3_;
  const int p = R - tree * M3_;
  const int j = p / 6;
  const int t6 = p - j * 6;
  const int sib = (t6 >= 3) ? 1 : 0;
  const int g = t6 - sib * 3;
  const int cell = tree * 2 + sib;
  const int srow = g * H_ + j;
  const float* wi = pa.wih[cell] + (size_t)srow * H_;
  const float* wh = pa.whh[cell] + (size_t)srow * H_;
  bf16* di = wihp + (size_t)R * H_;
  bf16* dh = whhp + (size_t)R * H_;
  const int k0 = threadIdx.x * 8;
  #pragma unroll
  for (int i = 0; i < 8; ++i) {
    di[k0 + i] = __float2bfloat16(wi[k0 + i]);
    dh[k0 + i] = __float2bfloat16(wh[k0 + i]);
  }
  if (threadIdx.x == 0) {
    float bi = pa.bih[cell][srow], bh = pa.bhh[cell][srow];
    bgi[R]  = bi + (g < 2 ? bh : 0.f);
    bghn[R] = (g == 2 ? bh : 0.f);
  }
}

__global__ void k_gather_x(const int* __restrict__ nodes, const float* __restrict__ emb,
                           bf16* __restrict__ X) {
  int i = blockIdx.x * 256 + threadIdx.x;
  if (i < SD_ * H_) {
    int sd = i >> 9, k = i & 511;
    X[i] = __float2bfloat16(emb[(size_t)nodes[sd] * H_ + k]);
  }
}

__global__ void k_cvt_bf16(const float* __restrict__ src, bf16* __restrict__ dst, int n) {
  int i = blockIdx.x * 256 + threadIdx.x;
  if (i < n) dst[i] = __float2bfloat16(src[i]);
}

__global__ void k_init_h(const float* __restrict__ init, float* __restrict__ hf,
                         bf16* __restrict__ hb0) {
  int i = blockIdx.x * 256 + threadIdx.x;
  if (i < D_ * H_) { float v = init[i]; hf[i] = v; hb0[i] = __float2bfloat16(v); }
}

// ---------------------------------------------------------------------------
// Generic bf16 GEMM: C(M,N) f32 = A(M,K=512) @ B(N,K=512)^T + bias
// 128x128 tile, BK=64, 4 waves of 64x64, XOR-swizzled LDS (row&7)<<4.
// ---------------------------------------------------------------------------
template<bool BIAS_ON_M, bool GUARD_N>
__global__ __launch_bounds__(256) void k_gemm(const bf16* __restrict__ A,
                                              const bf16* __restrict__ B,
                                              const float* __restrict__ bias,
                                              float* __restrict__ C, int M, int N) {
  constexpr int K = 512;
  __shared__ bf16 As[128 * 64];
  __shared__ bf16 Bs[128 * 64];
  const int tid = threadIdx.x;
  const int l = tid & 63, w = tid >> 6;
  const int gm0 = blockIdx.y * 128, gn0 = blockIdx.x * 128;
  const int wr = w >> 1, wc = w & 1;
  f32x4 acc[4][4];
  #pragma unroll
  for (int a = 0; a < 4; ++a)
    #pragma unroll
    for (int b = 0; b < 4; ++b) acc[a][b] = zero4();

  const int srow = tid >> 1;
  const int kc0 = (tid & 1) * 32;

  for (int kt = 0; kt < K; kt += 64) {
    #pragma unroll
    for (int c = 0; c < 4; ++c) {
      int kl = kc0 + c * 8;
      short8 v = *reinterpret_cast<const short8*>(&A[(size_t)(gm0 + srow) * K + kt + kl]);
      int off = srow * 128 + ((kl * 2) ^ ((srow & 7) << 4));
      *reinterpret_cast<short8*>(reinterpret_cast<char*>(As) + off) = v;
    }
    #pragma unroll
    for (int c = 0; c < 4; ++c) {
      int kl = kc0 + c * 8;
      int brow = gn0 + srow;
      if (GUARD_N) brow = brow < N ? brow : N - 1;
      short8 v = *reinterpret_cast<const short8*>(&B[(size_t)brow * K + kt + kl]);
      int off = srow * 128 + ((kl * 2) ^ ((srow & 7) << 4));
      *reinterpret_cast<short8*>(reinterpret_cast<char*>(Bs) + off) = v;
    }
    __syncthreads();
    #pragma unroll
    for (int kk = 0; kk < 64; kk += 32) {
      short8 af[4], bfr[4];
      const int kb = (kk + (l >> 4) * 8) * 2;
      #pragma unroll
      for (int mt = 0; mt < 4; ++mt) {
        int row = wr * 64 + mt * 16 + (l & 15);
        int off = row * 128 + (kb ^ ((row & 7) << 4));
        af[mt] = *reinterpret_cast<const short8*>(reinterpret_cast<const char*>(As) + off);
      }
      #pragma unroll
      for (int nt = 0; nt < 4; ++nt) {
        int row = wc * 64 + nt * 16 + (l & 15);
        int off = row * 128 + (kb ^ ((row & 7) << 4));
        bfr[nt] = *reinterpret_cast<const short8*>(reinterpret_cast<const char*>(Bs) + off);
      }
      #pragma unroll
      for (int mt = 0; mt < 4; ++mt)
        #pragma unroll
        for (int nt = 0; nt < 4; ++nt)
          acc[mt][nt] = __builtin_amdgcn_mfma_f32_16x16x32_bf16(af[mt], bfr[nt], acc[mt][nt], 0, 0, 0);
    }
    __syncthreads();
  }
  #pragma unroll
  for (int mt = 0; mt < 4; ++mt)
    #pragma unroll
    for (int nt = 0; nt < 4; ++nt)
      #pragma unroll
      for (int i = 0; i < 4; ++i) {
        int row = wr * 64 + mt * 16 + (l >> 4) * 4 + i;
        int col = wc * 64 + nt * 16 + (l & 15);
        int gr = gm0 + row, gc = gn0 + col;
        if (!GUARD_N || gc < N) {
          float v = acc[mt][nt][i] + (BIAS_ON_M ? bias[gr] : bias[gc]);
          C[(size_t)gr * N + gc] = v;
        }
      }
}

// ---------------------------------------------------------------------------
// Cooperative tree-GRU recurrence. 128 WGs = 64 M-slices (48 gate rows) x 2
// d-halves. Whh slice register-resident (12 short8/lane). Per step: ghT =
// Whh_perm @ h^T via 4-wave K-split MFMA, LDS reduce, fused GRU epilogue,
// grid.sync().
// ---------------------------------------------------------------------------
__global__ __launch_bounds__(256) void k_recur(const bf16* __restrict__ whhp,
                                               const float* __restrict__ giT,
                                               const float* __restrict__ bghn,
                                               const int* __restrict__ edges,
                                               float* __restrict__ hf,
                                               bf16* __restrict__ hb0,
                                               bf16* __restrict__ hb1,
                                               bf16* __restrict__ outs) {
  cg::grid_group grid = cg::this_grid();
  __shared__ float lds_p[4][64][48];   // [wave][d_local][gate_row_local]
  const int tid = threadIdx.x, l = tid & 63, w = tid >> 6;
  const int ms = blockIdx.x >> 1, dh = blockIdx.x & 1;
  const int kw = w * 128;

  short8 areg[3][4];
  #pragma unroll
  for (int mt = 0; mt < 3; ++mt)
    #pragma unroll
    for (int ks = 0; ks < 4; ++ks) {
      int row = ms * 48 + mt * 16 + (l & 15);
      int k = kw + ks * 32 + (l >> 4) * 8;
      areg[mt][ks] = *reinterpret_cast<const short8*>(&whhp[(size_t)row * H_ + k]);
    }

  bf16* hbuf[2] = {hb0, hb1};
  #pragma unroll 1
  for (int t = 0; t < S_; ++t) {
    const bf16* hb = hbuf[t & 1];
    bf16* hnb = hbuf[(t + 1) & 1];
    f32x4 acc[3][4];
    #pragma unroll
    for (int a = 0; a < 3; ++a)
      #pragma unroll
      for (int b = 0; b < 4; ++b) acc[a][b] = zero4();
    #pragma unroll
    for (int ks = 0; ks < 4; ++ks) {
      short8 bfr[4];
      #pragma unroll
      for (int nt = 0; nt < 4; ++nt) {
        int d = dh * 64 + nt * 16 + (l & 15);
        int k = kw + ks * 32 + (l >> 4) * 8;
        bfr[nt] = *reinterpret_cast<const short8*>(&hb[d * H_ + k]);
      }
      #pragma unroll
      for (int mt = 0; mt < 3; ++mt)
        #pragma unroll
        for (int nt = 0; nt < 4; ++nt)
          acc[mt][nt] = __builtin_amdgcn_mfma_f32_16x16x32_bf16(areg[mt][ks], bfr[nt], acc[mt][nt], 0, 0, 0);
    }
    __syncthreads();   // prior-iteration epilogue reads of lds_p complete
    #pragma unroll
    for (int mt = 0; mt < 3; ++mt)
      #pragma unroll
      for (int nt = 0; nt < 4; ++nt) {
        int col = nt * 16 + (l & 15);
        int r0 = mt * 16 + (l >> 4) * 4;
        *reinterpret_cast<f32x4*>(&lds_p[w][col][r0]) = acc[mt][nt];
      }
    __syncthreads();
    // epilogue: 512 outputs (8 h-cols x 64 d), 2 per thread
    for (int o = tid; o < 512; o += 256) {
      int jloc = o >> 6, dloc = o & 63;
      float gh[6];
      #pragma unroll
      for (int q = 0; q < 6; ++q) {
        int r = jloc * 6 + q;
        float s = lds_p[0][dloc][r] + lds_p[1][dloc][r] + lds_p[2][dloc][r] + lds_p[3][dloc][r];
        gh[q] = s + bghn[ms * 48 + r];
      }
      int dg = dh * 64 + dloc;
      int jg = ms * 8 + jloc;
      const float* gp = giT + (size_t)(ms * 48 + jloc * 6) * SD_ + t * D_ + dg;
      float rc = sigm(gp[0 * (size_t)SD_] + gh[0]);
      float zc = sigm(gp[1 * (size_t)SD_] + gh[1]);
      float nc = tanhf(gp[2 * (size_t)SD_] + rc * gh[2]);
      float rs = sigm(gp[3 * (size_t)SD_] + gh[3]);
      float zs = sigm(gp[4 * (size_t)SD_] + gh[4]);
      float ns = tanhf(gp[5 * (size_t)SD_] + rs * gh[5]);
      float ho = hf[dg * H_ + jg];
      float hc = (1.f - zc) * nc + zc * ho;
      float hs = (1.f - zs) * ns + zs * ho;
      float hv = (edges[t * D_ + dg] != 0) ? hc : hs;
      hf[dg * H_ + jg] = hv;
      hnb[dg * H_ + jg] = __float2bfloat16(hv);
      if (outs) outs[(size_t)t * (D_ * H_) + dg * H_ + jg] = __float2bfloat16(hv);
    }
    __threadfence();
    grid.sync();
  }
}

// mean/logv/z from final encoder h (f32)
__global__ __launch_bounds__(256) void k_latent(const float* __restrict__ hf,
    const float* __restrict__ h2mW, const float* __restrict__ h2mB,
    const float* __restrict__ h2lW, const float* __restrict__ h2lB,
    const float* __restrict__ eps, float* __restrict__ om, float* __restrict__ ov,
    float* __restrict__ oz, float* __restrict__ zf) {
  __shared__ float hrow[H_];
  const int d = blockIdx.x;
  for (int k = threadIdx.x; k < H_; k += 256) hrow[k] = hf[d * H_ + k];
  __syncthreads();
  const int lc = threadIdx.x;   // L_ == 256
  const float* wm = &h2mW[(size_t)lc * H_];
  const float* wl = &h2lW[(size_t)lc * H_];
  float m = 0.f, v = 0.f;
  for (int k = 0; k < H_; ++k) { float h = hrow[k]; m += h * wm[k]; v += h * wl[k]; }
  m += h2mB[lc]; v += h2lB[lc];
  float z = eps[d * L_ + lc] * __expf(0.5f * v) + m;
  om[d * L_ + lc] = m; ov[d * L_ + lc] = v; oz[d * L_ + lc] = z; zf[d * L_ + lc] = z;
}

__global__ __launch_bounds__(256) void k_decinit(const float* __restrict__ zf,
    const float* __restrict__ l2hW, const float* __restrict__ l2hB,
    float* __restrict__ hf, bf16* __restrict__ hb0) {
  __shared__ float zrow[L_];
  const int d = blockIdx.x;
  if (threadIdx.x < L_) zrow[threadIdx.x] = zf[d * L_ + threadIdx.x];
  __syncthreads();
  for (int j = threadIdx.x; j < H_; j += 256) {
    const float* wr = &l2hW[(size_t)j * L_];
    float a = 0.f;
    for (int k = 0; k < L_; ++k) a += zrow[k] * wr[k];
    a += l2hB[j];
    hf[d * H_ + j] = a;
    hb0[d * H_ + j] = __float2bfloat16(a);
  }
}

__global__ __launch_bounds__(256) void k_logsoftmax(float* __restrict__ lg) {
  __shared__ float buf[V_];
  __shared__ float redm[4], reds[4];
  const size_t base = (size_t)blockIdx.x * V_;
  const int tid = threadIdx.x;
  float lmax = -3.0e38f;
  for (int i = tid; i < V_; i += 256) { float x = lg[base + i]; buf[i] = x; lmax = fmaxf(lmax, x); }
  #pragma unroll
  for (int off = 32; off > 0; off >>= 1) lmax = fmaxf(lmax, __shfl_down(lmax, off, 64));
  if ((tid & 63) == 0) redm[tid >> 6] = lmax;
  __syncthreads();
  const float gmax = fmaxf(fmaxf(redm[0], redm[1]), fmaxf(redm[2], redm[3]));
  float s = 0.f;
  for (int i = tid; i < V_; i += 256) s += __expf(buf[i] - gmax);
  #pragma unroll
  for (int off = 32; off > 0; off >>= 1) s += __shfl_down(s, off, 64);
  if ((tid & 63) == 0) reds[tid >> 6] = s;
  __syncthreads();
  const float lse = gmax + __logf(reds[0] + reds[1] + reds[2] + reds[3]);
  for (int i = tid; i < V_; i += 256) lg[base + i] = buf[i] - lse;
}

// ---------------------------------------------------------------------------
extern "C" void kernel_launch(void* const* d_in, const int* in_sizes, int n_in,
                              void* d_out, int out_size, void* d_ws, size_t ws_size,
                              hipStream_t stream) {
  const int* nodes = (const int*)d_in[0];
  const int* edges = (const int*)d_in[1];   // assumed int32 (bool in reference)
  const float* emb = (const float*)d_in[2];
  PrepArgs pa;
  for (int c = 0; c < 4; ++c) {
    pa.wih[c] = (const float*)d_in[3 + c * 4 + 0];
    pa.whh[c] = (const float*)d_in[3 + c * 4 + 1];
    pa.bih[c] = (const float*)d_in[3 + c * 4 + 2];
    pa.bhh[c] = (const float*)d_in[3 + c * 4 + 3];
  }
  const float* h2mW = (const float*)d_in[19];
  const float* h2mB = (const float*)d_in[20];
  const float* h2lW = (const float*)d_in[21];
  const float* h2lB = (const float*)d_in[22];
  const float* l2hW = (const float*)d_in[23];
  const float* l2hB = (const float*)d_in[24];
  const float* o2vW = (const float*)d_in[25];
  const float* o2vB = (const float*)d_in[26];
  const float* enc_init = (const float*)d_in[27];
  const float* eps = (const float*)d_in[28];

  char* ws = (char*)d_ws;
  size_t off = 0;
  bf16* WIHP = (bf16*)(ws + off); off += (size_t)2 * M3_ * H_ * 2;   // 6 MiB
  bf16* WHHP = (bf16*)(ws + off); off += (size_t)2 * M3_ * H_ * 2;
  float* BGI  = (float*)(ws + off); off += (size_t)2 * M3_ * 4;
  float* BGHN = (float*)(ws + off); off += (size_t)2 * M3_ * 4;
  bf16* XB   = (bf16*)(ws + off); off += (size_t)SD_ * H_ * 2;
  bf16* O2VB = (bf16*)(ws + off); off += (size_t)V_ * H_ * 2;
  float* HF  = (float*)(ws + off); off += (size_t)D_ * H_ * 4;
  bf16* HB0  = (bf16*)(ws + off); off += (size_t)D_ * H_ * 2;
  bf16* HB1  = (bf16*)(ws + off); off += (size_t)D_ * H_ * 2;
  float* ZF  = (float*)(ws + off); off += (size_t)D_ * L_ * 4;
  bf16* OUTS = (bf16*)(ws + off); off += (size_t)S_ * D_ * H_ * 2;
  float* GIT = (float*)(ws + off); off += (size_t)M3_ * SD_ * 4;     // 72 MiB
  (void)ws_size; (void)in_sizes; (void)n_in; (void)out_size;

  float* out_logp = (float*)d_out;
  float* out_mean = out_logp + (size_t)SD_ * V_;
  float* out_logv = out_mean + (size_t)D_ * L_;
  float* out_z    = out_logv + (size_t)D_ * L_;

  // prep
  hipLaunchKernelGGL(k_prep_w, dim3(2 * M3_), dim3(64), 0, stream, pa, WIHP, WHHP, BGI, BGHN);
  hipLaunchKernelGGL(k_gather_x, dim3((SD_ * H_ + 255) / 256), dim3(256), 0, stream, nodes, emb, XB);
  hipLaunchKernelGGL(k_cvt_bf16, dim3((V_ * H_ + 255) / 256), dim3(256), 0, stream, o2vW, O2VB, V_ * H_);
  hipLaunchKernelGGL(k_init_h, dim3((D_ * H_ + 255) / 256), dim3(256), 0, stream, enc_init, HF, HB0);

  // encoder: gi GEMM + recurrence
  hipLaunchKernelGGL((k_gemm<true, false>), dim3(SD_ / 128, M3_ / 128), dim3(256), 0, stream,
                     WIHP, XB, BGI, GIT, M3_, SD_);
  {
    const bf16* whhpE = WHHP; const float* gitp = GIT; const float* bghnE = BGHN;
    float* hfp = HF; bf16* hb0 = HB0; bf16* hb1 = HB1; bf16* outs0 = nullptr;
    const int* edg = edges;
    void* args[] = {(void*)&whhpE, (void*)&gitp, (void*)&bghnE, (void*)&edg,
                    (void*)&hfp, (void*)&hb0, (void*)&hb1, (void*)&outs0};
    hipLaunchCooperativeKernel((const void*)k_recur, dim3(128), dim3(256), args, 0, stream);
  }

  hipLaunchKernelGGL(k_latent, dim3(D_), dim3(256), 0, stream, HF, h2mW, h2mB, h2lW, h2lB,
                     eps, out_mean, out_logv, out_z, ZF);
  hipLaunchKernelGGL(k_decinit, dim3(D_), dim3(256), 0, stream, ZF, l2hW, l2hB, HF, HB0);

  // decoder: gi GEMM + recurrence (writes OUTS)
  hipLaunchKernelGGL((k_gemm<true, false>), dim3(SD_ / 128, M3_ / 128), dim3(256), 0, stream,
                     WIHP + (size_t)M3_ * H_, XB, BGI + M3_, GIT, M3_, SD_);
  {
    const bf16* whhpD = WHHP + (size_t)M3_ * H_; const float* gitp = GIT;
    const float* bghnD = BGHN + M3_;
    float* hfp = HF; bf16* hb0 = HB0; bf16* hb1 = HB1; bf16* outsP = OUTS;
    const int* edg = edges;
    void* args[] = {(void*)&whhpD, (void*)&gitp, (void*)&bghnD, (void*)&edg,
                    (void*)&hfp, (void*)&hb0, (void*)&hb1, (void*)&outsP};
    hipLaunchCooperativeKernel((const void*)k_recur, dim3(128), dim3(256), args, 0, stream);
  }

  // logits + log_softmax (in-place in d_out)
  hipLaunchKernelGGL((k_gemm<false, true>), dim3((V_ + 127) / 128, SD_ / 128), dim3(256), 0, stream,
                     OUTS, O2VB, o2vB, out_logp, SD_, V_);
  hipLaunchKernelGGL(k_logsoftmax, dim3(SD_), dim3(256), 0, stream, out_logp);
}

// Round 2
// 1631.005 us; speedup vs baseline: 2.7457x; 2.7457x over previous
//
#include <hip/hip_runtime.h>
#include <hip/hip_bf16.h>

#define S_ 48
#define D_ 128
#define H_ 512
#define L_ 256
#define V_ 6000
#define SD_ 6144      // S*D
#define M3_ 3072      // 6*H permuted gate rows per tree
#define NWG_HALF 64   // WGs per dh-half barrier group

typedef __attribute__((ext_vector_type(8))) short short8;
typedef __attribute__((ext_vector_type(4))) float f32x4;
typedef __hip_bfloat16 bf16;

__device__ __forceinline__ float sigm(float x) { return 1.0f / (1.0f + __expf(-x)); }
__device__ __forceinline__ f32x4 zero4() { f32x4 z; z[0]=0.f; z[1]=0.f; z[2]=0.f; z[3]=0.f; return z; }

// ---------------------------------------------------------------------------
// Prep kernels (unchanged from R1)
// ---------------------------------------------------------------------------
struct PrepArgs {
  const float* wih[4]; const float* whh[4];
  const float* bih[4]; const float* bhh[4];
};

__global__ __launch_bounds__(64) void k_prep_w(PrepArgs pa, bf16* __restrict__ wihp,
                                               bf16* __restrict__ whhp,
                                               float* __restrict__ bgi,
                                               float* __restrict__ bghn) {
  const int R = blockIdx.x;
  const int tree = R / M3_;
  const int p = R - tree * M3_;
  const int j = p / 6;
  const int t6 = p - j * 6;
  const int sib = (t6 >= 3) ? 1 : 0;
  const int g = t6 - sib * 3;
  const int cell = tree * 2 + sib;
  const int srow = g * H_ + j;
  const float* wi = pa.wih[cell] + (size_t)srow * H_;
  const float* wh = pa.whh[cell] + (size_t)srow * H_;
  bf16* di = wihp + (size_t)R * H_;
  bf16* dh = whhp + (size_t)R * H_;
  const int k0 = threadIdx.x * 8;
  #pragma unroll
  for (int i = 0; i < 8; ++i) {
    di[k0 + i] = __float2bfloat16(wi[k0 + i]);
    dh[k0 + i] = __float2bfloat16(wh[k0 + i]);
  }
  if (threadIdx.x == 0) {
    float bi = pa.bih[cell][srow], bh = pa.bhh[cell][srow];
    bgi[R]  = bi + (g < 2 ? bh : 0.f);
    bghn[R] = (g == 2 ? bh : 0.f);
  }
}

__global__ void k_gather_x(const int* __restrict__ nodes, const float* __restrict__ emb,
                           bf16* __restrict__ X) {
  int i = blockIdx.x * 256 + threadIdx.x;
  if (i < SD_ * H_) {
    int sd = i >> 9, k = i & 511;
    X[i] = __float2bfloat16(emb[(size_t)nodes[sd] * H_ + k]);
  }
}

__global__ void k_cvt_bf16(const float* __restrict__ src, bf16* __restrict__ dst, int n) {
  int i = blockIdx.x * 256 + threadIdx.x;
  if (i < n) dst[i] = __float2bfloat16(src[i]);
}

__global__ void k_init_h(const float* __restrict__ init, float* __restrict__ hf,
                         bf16* __restrict__ hb0) {
  int i = blockIdx.x * 256 + threadIdx.x;
  if (i < D_ * H_) { float v = init[i]; hf[i] = v; hb0[i] = __float2bfloat16(v); }
}

// ---------------------------------------------------------------------------
// Generic bf16 GEMM (unchanged): C(M,N) f32 = A(M,512) @ B(N,512)^T + bias
// ---------------------------------------------------------------------------
template<bool BIAS_ON_M, bool GUARD_N>
__global__ __launch_bounds__(256) void k_gemm(const bf16* __restrict__ A,
                                              const bf16* __restrict__ B,
                                              const float* __restrict__ bias,
                                              float* __restrict__ C, int M, int N) {
  constexpr int K = 512;
  __shared__ bf16 As[128 * 64];
  __shared__ bf16 Bs[128 * 64];
  const int tid = threadIdx.x;
  const int l = tid & 63, w = tid >> 6;
  const int gm0 = blockIdx.y * 128, gn0 = blockIdx.x * 128;
  const int wr = w >> 1, wc = w & 1;
  f32x4 acc[4][4];
  #pragma unroll
  for (int a = 0; a < 4; ++a)
    #pragma unroll
    for (int b = 0; b < 4; ++b) acc[a][b] = zero4();

  const int srow = tid >> 1;
  const int kc0 = (tid & 1) * 32;

  for (int kt = 0; kt < K; kt += 64) {
    #pragma unroll
    for (int c = 0; c < 4; ++c) {
      int kl = kc0 + c * 8;
      short8 v = *reinterpret_cast<const short8*>(&A[(size_t)(gm0 + srow) * K + kt + kl]);
      int off = srow * 128 + ((kl * 2) ^ ((srow & 7) << 4));
      *reinterpret_cast<short8*>(reinterpret_cast<char*>(As) + off) = v;
    }
    #pragma unroll
    for (int c = 0; c < 4; ++c) {
      int kl = kc0 + c * 8;
      int brow = gn0 + srow;
      if (GUARD_N) brow = brow < N ? brow : N - 1;
      short8 v = *reinterpret_cast<const short8*>(&B[(size_t)brow * K + kt + kl]);
      int off = srow * 128 + ((kl * 2) ^ ((srow & 7) << 4));
      *reinterpret_cast<short8*>(reinterpret_cast<char*>(Bs) + off) = v;
    }
    __syncthreads();
    #pragma unroll
    for (int kk = 0; kk < 64; kk += 32) {
      short8 af[4], bfr[4];
      const int kb = (kk + (l >> 4) * 8) * 2;
      #pragma unroll
      for (int mt = 0; mt < 4; ++mt) {
        int row = wr * 64 + mt * 16 + (l & 15);
        int off = row * 128 + (kb ^ ((row & 7) << 4));
        af[mt] = *reinterpret_cast<const short8*>(reinterpret_cast<const char*>(As) + off);
      }
      #pragma unroll
      for (int nt = 0; nt < 4; ++nt) {
        int row = wc * 64 + nt * 16 + (l & 15);
        int off = row * 128 + (kb ^ ((row & 7) << 4));
        bfr[nt] = *reinterpret_cast<const short8*>(reinterpret_cast<const char*>(Bs) + off);
      }
      #pragma unroll
      for (int mt = 0; mt < 4; ++mt)
        #pragma unroll
        for (int nt = 0; nt < 4; ++nt)
          acc[mt][nt] = __builtin_amdgcn_mfma_f32_16x16x32_bf16(af[mt], bfr[nt], acc[mt][nt], 0, 0, 0);
    }
    __syncthreads();
  }
  #pragma unroll
  for (int mt = 0; mt < 4; ++mt)
    #pragma unroll
    for (int nt = 0; nt < 4; ++nt)
      #pragma unroll
      for (int i = 0; i < 4; ++i) {
        int row = wr * 64 + mt * 16 + (l >> 4) * 4 + i;
        int col = wc * 64 + nt * 16 + (l & 15);
        int gr = gm0 + row, gc = gn0 + col;
        if (!GUARD_N || gc < N) {
          float v = acc[mt][nt][i] + (BIAS_ON_M ? bias[gr] : bias[gc]);
          C[(size_t)gr * N + gc] = v;
        }
      }
}

// ---------------------------------------------------------------------------
// Cooperative tree-GRU recurrence with CUSTOM lightweight barrier.
// 128 WGs = 64 M-slices x 2 d-halves; only same-dh WGs communicate, so the
// barrier is two independent 64-WG groups with per-step counters.
// h-state lives in registers; bghn hoisted; giT/edges prefetched 1 step ahead.
// ---------------------------------------------------------------------------
__global__ __launch_bounds__(256) void k_recur(const bf16* __restrict__ whhp,
                                               const float* __restrict__ giT,
                                               const float* __restrict__ bghn,
                                               const int* __restrict__ edges,
                                               float* __restrict__ hf,
                                               bf16* __restrict__ hb0,
                                               bf16* __restrict__ hb1,
                                               bf16* __restrict__ outs,
                                               unsigned* __restrict__ bar) {
  __shared__ float lds_p[4][64][49];   // 49-pad: conflict-free dloc-strided access
  const int tid = threadIdx.x, l = tid & 63, w = tid >> 6;
  const int ms = blockIdx.x >> 1, dh = blockIdx.x & 1;
  const int kw = w * 128;

  // register-resident Whh slice: 48 rows x 128 k per wave (full K via 4-wave split)
  short8 areg[3][4];
  #pragma unroll
  for (int mt = 0; mt < 3; ++mt)
    #pragma unroll
    for (int ks = 0; ks < 4; ++ks) {
      int row = ms * 48 + mt * 16 + (l & 15);
      int k = kw + ks * 32 + (l >> 4) * 8;
      areg[mt][ks] = *reinterpret_cast<const short8*>(&whhp[(size_t)row * H_ + k]);
    }

  // per-thread output slots: s=0,1 -> (jloc, dloc)
  int jl[2], dl[2], dg[2], jg[2];
  float bgh[2][6], hstate[2];
  const float* gbase[2];
  #pragma unroll
  for (int s = 0; s < 2; ++s) {
    int o = tid + s * 256;
    jl[s] = o >> 6; dl[s] = o & 63;
    dg[s] = dh * 64 + dl[s];
    jg[s] = ms * 8 + jl[s];
    #pragma unroll
    for (int q = 0; q < 6; ++q) bgh[s][q] = bghn[ms * 48 + jl[s] * 6 + q];
    hstate[s] = hf[dg[s] * H_ + jg[s]];
    gbase[s] = giT + (size_t)(ms * 48 + jl[s] * 6) * SD_ + dg[s];
  }

  // prefetch step-0 gi + edges
  float gic[2][6]; int edc[2];
  #pragma unroll
  for (int s = 0; s < 2; ++s) {
    #pragma unroll
    for (int q = 0; q < 6; ++q) gic[s][q] = gbase[s][(size_t)q * SD_];
    edc[s] = edges[dg[s]];
  }

  bf16* hbuf[2] = {hb0, hb1};
  #pragma unroll 1
  for (int t = 0; t < S_; ++t) {
    // prefetch NEXT step's gi + edges (independent of h; hides under MFMA/epilogue)
    float gin[2][6]; int edn[2];
    if (t + 1 < S_) {
      #pragma unroll
      for (int s = 0; s < 2; ++s) {
        #pragma unroll
        for (int q = 0; q < 6; ++q) gin[s][q] = gbase[s][(size_t)q * SD_ + (t + 1) * D_];
        edn[s] = edges[(t + 1) * D_ + dg[s]];
      }
    } else {
      #pragma unroll
      for (int s = 0; s < 2; ++s) { edn[s] = 0;
        #pragma unroll
        for (int q = 0; q < 6; ++q) gin[s][q] = 0.f; }
    }

    const bf16* hb = hbuf[t & 1];
    bf16* hnb = hbuf[(t + 1) & 1];
    f32x4 acc[3][4];
    #pragma unroll
    for (int a = 0; a < 3; ++a)
      #pragma unroll
      for (int b = 0; b < 4; ++b) acc[a][b] = zero4();
    #pragma unroll
    for (int ks = 0; ks < 4; ++ks) {
      short8 bfr[4];
      #pragma unroll
      for (int nt = 0; nt < 4; ++nt) {
        int d = dh * 64 + nt * 16 + (l & 15);
        int k = kw + ks * 32 + (l >> 4) * 8;
        bfr[nt] = *reinterpret_cast<const short8*>(&hb[d * H_ + k]);
      }
      #pragma unroll
      for (int mt = 0; mt < 3; ++mt)
        #pragma unroll
        for (int nt = 0; nt < 4; ++nt)
          acc[mt][nt] = __builtin_amdgcn_mfma_f32_16x16x32_bf16(areg[mt][ks], bfr[nt], acc[mt][nt], 0, 0, 0);
    }
    __syncthreads();   // prior-iteration epilogue reads of lds_p complete
    #pragma unroll
    for (int mt = 0; mt < 3; ++mt)
      #pragma unroll
      for (int nt = 0; nt < 4; ++nt) {
        int col = nt * 16 + (l & 15);
        int r0 = mt * 16 + (l >> 4) * 4;
        #pragma unroll
        for (int i = 0; i < 4; ++i) lds_p[w][col][r0 + i] = acc[mt][nt][i];
      }
    __syncthreads();
    // epilogue: 512 outputs/WG, 2 per thread, all state in registers
    #pragma unroll
    for (int s = 0; s < 2; ++s) {
      float gh[6];
      #pragma unroll
      for (int q = 0; q < 6; ++q) {
        int r = jl[s] * 6 + q;
        gh[q] = lds_p[0][dl[s]][r] + lds_p[1][dl[s]][r] + lds_p[2][dl[s]][r]
              + lds_p[3][dl[s]][r] + bgh[s][q];
      }
      float rc = sigm(gic[s][0] + gh[0]);
      float zc = sigm(gic[s][1] + gh[1]);
      float nc = tanhf(gic[s][2] + rc * gh[2]);
      float rs = sigm(gic[s][3] + gh[3]);
      float zs = sigm(gic[s][4] + gh[4]);
      float ns = tanhf(gic[s][5] + rs * gh[5]);
      float ho = hstate[s];
      float hc = (1.f - zc) * nc + zc * ho;
      float hs = (1.f - zs) * ns + zs * ho;
      float hv = (edc[s] != 0) ? hc : hs;
      hstate[s] = hv;
      hnb[dg[s] * H_ + jg[s]] = __float2bfloat16(hv);
      if (outs) outs[(size_t)t * (D_ * H_) + dg[s] * H_ + jg[s]] = __float2bfloat16(hv);
    }
    // rotate prefetch registers
    #pragma unroll
    for (int s = 0; s < 2; ++s) { edc[s] = edn[s];
      #pragma unroll
      for (int q = 0; q < 6; ++q) gic[s][q] = gin[s][q]; }

    if (t + 1 < S_) {
      __syncthreads();           // all threads' h stores drained to L2
      if (tid == 0) {
        unsigned* c = bar + t * 2 + dh;
        __hip_atomic_fetch_add(c, 1u, __ATOMIC_RELEASE, __HIP_MEMORY_SCOPE_AGENT);
        while (__hip_atomic_load(c, __ATOMIC_RELAXED, __HIP_MEMORY_SCOPE_AGENT) < NWG_HALF)
          __builtin_amdgcn_s_sleep(2);
        __builtin_amdgcn_fence(__ATOMIC_ACQUIRE, "agent");
      }
      __syncthreads();
    }
  }
  // final h (f32) for k_latent
  #pragma unroll
  for (int s = 0; s < 2; ++s) hf[dg[s] * H_ + jg[s]] = hstate[s];
}

// mean/logv/z from final encoder h (f32)
__global__ __launch_bounds__(256) void k_latent(const float* __restrict__ hf,
    const float* __restrict__ h2mW, const float* __restrict__ h2mB,
    const float* __restrict__ h2lW, const float* __restrict__ h2lB,
    const float* __restrict__ eps, float* __restrict__ om, float* __restrict__ ov,
    float* __restrict__ oz, float* __restrict__ zf) {
  __shared__ float hrow[H_];
  const int d = blockIdx.x;
  for (int k = threadIdx.x; k < H_; k += 256) hrow[k] = hf[d * H_ + k];
  __syncthreads();
  const int lc = threadIdx.x;   // L_ == 256
  const float* wm = &h2mW[(size_t)lc * H_];
  const float* wl = &h2lW[(size_t)lc * H_];
  float m = 0.f, v = 0.f;
  for (int k = 0; k < H_; ++k) { float h = hrow[k]; m += h * wm[k]; v += h * wl[k]; }
  m += h2mB[lc]; v += h2lB[lc];
  float z = eps[d * L_ + lc] * __expf(0.5f * v) + m;
  om[d * L_ + lc] = m; ov[d * L_ + lc] = v; oz[d * L_ + lc] = z; zf[d * L_ + lc] = z;
}

__global__ __launch_bounds__(256) void k_decinit(const float* __restrict__ zf,
    const float* __restrict__ l2hW, const float* __restrict__ l2hB,
    float* __restrict__ hf, bf16* __restrict__ hb0) {
  __shared__ float zrow[L_];
  const int d = blockIdx.x;
  if (threadIdx.x < L_) zrow[threadIdx.x] = zf[d * L_ + threadIdx.x];
  __syncthreads();
  for (int j = threadIdx.x; j < H_; j += 256) {
    const float* wr = &l2hW[(size_t)j * L_];
    float a = 0.f;
    for (int k = 0; k < L_; ++k) a += zrow[k] * wr[k];
    a += l2hB[j];
    hf[d * H_ + j] = a;
    hb0[d * H_ + j] = __float2bfloat16(a);
  }
}

__global__ __launch_bounds__(256) void k_logsoftmax(float* __restrict__ lg) {
  __shared__ float buf[V_];
  __shared__ float redm[4], reds[4];
  const size_t base = (size_t)blockIdx.x * V_;
  const int tid = threadIdx.x;
  float lmax = -3.0e38f;
  for (int i = tid; i < V_; i += 256) { float x = lg[base + i]; buf[i] = x; lmax = fmaxf(lmax, x); }
  #pragma unroll
  for (int off = 32; off > 0; off >>= 1) lmax = fmaxf(lmax, __shfl_down(lmax, off, 64));
  if ((tid & 63) == 0) redm[tid >> 6] = lmax;
  __syncthreads();
  const float gmax = fmaxf(fmaxf(redm[0], redm[1]), fmaxf(redm[2], redm[3]));
  float s = 0.f;
  for (int i = tid; i < V_; i += 256) s += __expf(buf[i] - gmax);
  #pragma unroll
  for (int off = 32; off > 0; off >>= 1) s += __shfl_down(s, off, 64);
  if ((tid & 63) == 0) reds[tid >> 6] = s;
  __syncthreads();
  const float lse = gmax + __logf(reds[0] + reds[1] + reds[2] + reds[3]);
  for (int i = tid; i < V_; i += 256) lg[base + i] = buf[i] - lse;
}

// ---------------------------------------------------------------------------
extern "C" void kernel_launch(void* const* d_in, const int* in_sizes, int n_in,
                              void* d_out, int out_size, void* d_ws, size_t ws_size,
                              hipStream_t stream) {
  const int* nodes = (const int*)d_in[0];
  const int* edges = (const int*)d_in[1];
  const float* emb = (const float*)d_in[2];
  PrepArgs pa;
  for (int c = 0; c < 4; ++c) {
    pa.wih[c] = (const float*)d_in[3 + c * 4 + 0];
    pa.whh[c] = (const float*)d_in[3 + c * 4 + 1];
    pa.bih[c] = (const float*)d_in[3 + c * 4 + 2];
    pa.bhh[c] = (const float*)d_in[3 + c * 4 + 3];
  }
  const float* h2mW = (const float*)d_in[19];
  const float* h2mB = (const float*)d_in[20];
  const float* h2lW = (const float*)d_in[21];
  const float* h2lB = (const float*)d_in[22];
  const float* l2hW = (const float*)d_in[23];
  const float* l2hB = (const float*)d_in[24];
  const float* o2vW = (const float*)d_in[25];
  const float* o2vB = (const float*)d_in[26];
  const float* enc_init = (const float*)d_in[27];
  const float* eps = (const float*)d_in[28];

  char* ws = (char*)d_ws;
  size_t off = 0;
  bf16* WIHP = (bf16*)(ws + off); off += (size_t)2 * M3_ * H_ * 2;
  bf16* WHHP = (bf16*)(ws + off); off += (size_t)2 * M3_ * H_ * 2;
  float* BGI  = (float*)(ws + off); off += (size_t)2 * M3_ * 4;
  float* BGHN = (float*)(ws + off); off += (size_t)2 * M3_ * 4;
  bf16* XB   = (bf16*)(ws + off); off += (size_t)SD_ * H_ * 2;
  bf16* O2VB = (bf16*)(ws + off); off += (size_t)V_ * H_ * 2;
  float* HF  = (float*)(ws + off); off += (size_t)D_ * H_ * 4;
  bf16* HB0  = (bf16*)(ws + off); off += (size_t)D_ * H_ * 2;
  bf16* HB1  = (bf16*)(ws + off); off += (size_t)D_ * H_ * 2;
  float* ZF  = (float*)(ws + off); off += (size_t)D_ * L_ * 4;
  bf16* OUTS = (bf16*)(ws + off); off += (size_t)S_ * D_ * H_ * 2;
  float* GIT = (float*)(ws + off); off += (size_t)M3_ * SD_ * 4;
  unsigned* BAR = (unsigned*)(ws + off); off += 2 * S_ * 2 * sizeof(unsigned);
  (void)ws_size; (void)in_sizes; (void)n_in; (void)out_size;

  float* out_logp = (float*)d_out;
  float* out_mean = out_logp + (size_t)SD_ * V_;
  float* out_logv = out_mean + (size_t)D_ * L_;
  float* out_z    = out_logv + (size_t)D_ * L_;

  // zero barrier counters (graph-capturable memset; ws is NOT re-poisoned
  // between replays, so this must run every call)
  hipMemsetAsync(BAR, 0, 2 * S_ * 2 * sizeof(unsigned), stream);

  // prep
  hipLaunchKernelGGL(k_prep_w, dim3(2 * M3_), dim3(64), 0, stream, pa, WIHP, WHHP, BGI, BGHN);
  hipLaunchKernelGGL(k_gather_x, dim3((SD_ * H_ + 255) / 256), dim3(256), 0, stream, nodes, emb, XB);
  hipLaunchKernelGGL(k_cvt_bf16, dim3((V_ * H_ + 255) / 256), dim3(256), 0, stream, o2vW, O2VB, V_ * H_);
  hipLaunchKernelGGL(k_init_h, dim3((D_ * H_ + 255) / 256), dim3(256), 0, stream, enc_init, HF, HB0);

  // encoder: gi GEMM + recurrence
  hipLaunchKernelGGL((k_gemm<true, false>), dim3(SD_ / 128, M3_ / 128), dim3(256), 0, stream,
                     WIHP, XB, BGI, GIT, M3_, SD_);
  {
    const bf16* whhpE = WHHP; const float* gitp = GIT; const float* bghnE = BGHN;
    float* hfp = HF; bf16* hb0 = HB0; bf16* hb1 = HB1; bf16* outs0 = nullptr;
    const int* edg = edges; unsigned* barE = BAR;
    void* args[] = {(void*)&whhpE, (void*)&gitp, (void*)&bghnE, (void*)&edg,
                    (void*)&hfp, (void*)&hb0, (void*)&hb1, (void*)&outs0, (void*)&barE};
    hipLaunchCooperativeKernel((const void*)k_recur, dim3(128), dim3(256), args, 0, stream);
  }

  hipLaunchKernelGGL(k_latent, dim3(D_), dim3(256), 0, stream, HF, h2mW, h2mB, h2lW, h2lB,
                     eps, out_mean, out_logv, out_z, ZF);
  hipLaunchKernelGGL(k_decinit, dim3(D_), dim3(256), 0, stream, ZF, l2hW, l2hB, HF, HB0);

  // decoder: gi GEMM + recurrence (writes OUTS)
  hipLaunchKernelGGL((k_gemm<true, false>), dim3(SD_ / 128, M3_ / 128), dim3(256), 0, stream,
                     WIHP + (size_t)M3_ * H_, XB, BGI + M3_, GIT, M3_, SD_);
  {
    const bf16* whhpD = WHHP + (size_t)M3_ * H_; const float* gitp = GIT;
    const float* bghnD = BGHN + M3_;
    float* hfp = HF; bf16* hb0 = HB0; bf16* hb1 = HB1; bf16* outsP = OUTS;
    const int* edg = edges; unsigned* barD = BAR + S_ * 2;
    void* args[] = {(void*)&whhpD, (void*)&gitp, (void*)&bghnD, (void*)&edg,
                    (void*)&hfp, (void*)&hb0, (void*)&hb1, (void*)&outsP, (void*)&barD};
    hipLaunchCooperativeKernel((const void*)k_recur, dim3(128), dim3(256), args, 0, stream);
  }

  // logits + log_softmax (in-place in d_out)
  hipLaunchKernelGGL((k_gemm<false, true>), dim3((V_ + 127) / 128, SD_ / 128), dim3(256), 0, stream,
                     OUTS, O2VB, o2vB, out_logp, SD_, V_);
  hipLaunchKernelGGL(k_logsoftmax, dim3(SD_), dim3(256), 0, stream, out_logp);
}

// Round 6
// 1018.323 us; speedup vs baseline: 4.3977x; 1.6017x over previous
//
#include <hip/hip_runtime.h>
#include <hip/hip_bf16.h>

#define S_ 48
#define D_ 128
#define H_ 512
#define L_ 256
#define V_ 6000
#define SD_ 6144      // S*D
#define M3_ 3072      // 6*H permuted gate rows per tree
#define NWG_HALF 64   // WGs per dh-half barrier group

typedef __attribute__((ext_vector_type(8))) short short8;
typedef __attribute__((ext_vector_type(4))) float f32x4;
typedef __hip_bfloat16 bf16;

__device__ __forceinline__ float sigm(float x) { return 1.0f / (1.0f + __expf(-x)); }
__device__ __forceinline__ f32x4 zero4() { f32x4 z; z[0]=0.f; z[1]=0.f; z[2]=0.f; z[3]=0.f; return z; }

// ---------------------------------------------------------------------------
// Prep kernels
// ---------------------------------------------------------------------------
struct PrepArgs {
  const float* wih[4]; const float* whh[4];
  const float* bih[4]; const float* bhh[4];
};

__global__ __launch_bounds__(64) void k_prep_w(PrepArgs pa, bf16* __restrict__ wihp,
                                               bf16* __restrict__ whhp,
                                               float* __restrict__ bgi,
                                               float* __restrict__ bghn) {
  const int R = blockIdx.x;
  const int tree = R / M3_;
  const int p = R - tree * M3_;
  const int j = p / 6;
  const int t6 = p - j * 6;
  const int sib = (t6 >= 3) ? 1 : 0;
  const int g = t6 - sib * 3;
  const int cell = tree * 2 + sib;
  const int srow = g * H_ + j;
  const float* wi = pa.wih[cell] + (size_t)srow * H_;
  const float* wh = pa.whh[cell] + (size_t)srow * H_;
  bf16* di = wihp + (size_t)R * H_;
  bf16* dh = whhp + (size_t)R * H_;
  const int k0 = threadIdx.x * 8;
  #pragma unroll
  for (int i = 0; i < 8; ++i) {
    di[k0 + i] = __float2bfloat16(wi[k0 + i]);
    dh[k0 + i] = __float2bfloat16(wh[k0 + i]);
  }
  if (threadIdx.x == 0) {
    float bi = pa.bih[cell][srow], bh = pa.bhh[cell][srow];
    bgi[R]  = bi + (g < 2 ? bh : 0.f);
    bghn[R] = (g == 2 ? bh : 0.f);
  }
}

__global__ void k_gather_x(const int* __restrict__ nodes, const float* __restrict__ emb,
                           bf16* __restrict__ X) {
  int i = blockIdx.x * 256 + threadIdx.x;
  if (i < SD_ * H_) {
    int sd = i >> 9, k = i & 511;
    X[i] = __float2bfloat16(emb[(size_t)nodes[sd] * H_ + k]);
  }
}

__global__ void k_cvt_bf16(const float* __restrict__ src, bf16* __restrict__ dst, int n) {
  int i = blockIdx.x * 256 + threadIdx.x;
  if (i < n) dst[i] = __float2bfloat16(src[i]);
}

// h(0): hf f32 [d][j]  +  HSTEPE[0] bf16 [jb][d][8]
__global__ void k_init_h(const float* __restrict__ init, float* __restrict__ hf,
                         bf16* __restrict__ hx0) {
  int i = blockIdx.x * 256 + threadIdx.x;
  if (i < D_ * H_) {
    int d = i >> 9, j = i & 511;
    float v = init[i];
    hf[i] = v;
    hx0[((j >> 3) * D_ + d) * 8 + (j & 7)] = __float2bfloat16(v);
  }
}

// ---------------------------------------------------------------------------
// Generic bf16 GEMM: C(M,N) = A(M,512) @ B(N,512)^T + bias; C f32 or bf16.
// ---------------------------------------------------------------------------
template<bool BIAS_ON_M, bool GUARD_N, bool CB16>
__global__ __launch_bounds__(256) void k_gemm(const bf16* __restrict__ A,
                                              const bf16* __restrict__ B,
                                              const float* __restrict__ bias,
                                              void* __restrict__ Cv, int M, int N) {
  constexpr int K = 512;
  __shared__ bf16 As[128 * 64];
  __shared__ bf16 Bs[128 * 64];
  const int tid = threadIdx.x;
  const int l = tid & 63, w = tid >> 6;
  const int gm0 = blockIdx.y * 128, gn0 = blockIdx.x * 128;
  const int wr = w >> 1, wc = w & 1;
  f32x4 acc[4][4];
  #pragma unroll
  for (int a = 0; a < 4; ++a)
    #pragma unroll
    for (int b = 0; b < 4; ++b) acc[a][b] = zero4();

  const int srow = tid >> 1;
  const int kc0 = (tid & 1) * 32;

  for (int kt = 0; kt < K; kt += 64) {
    #pragma unroll
    for (int c = 0; c < 4; ++c) {
      int kl = kc0 + c * 8;
      short8 v = *reinterpret_cast<const short8*>(&A[(size_t)(gm0 + srow) * K + kt + kl]);
      int off = srow * 128 + ((kl * 2) ^ ((srow & 7) << 4));
      *reinterpret_cast<short8*>(reinterpret_cast<char*>(As) + off) = v;
    }
    #pragma unroll
    for (int c = 0; c < 4; ++c) {
      int kl = kc0 + c * 8;
      int brow = gn0 + srow;
      if (GUARD_N) brow = brow < N ? brow : N - 1;
      short8 v = *reinterpret_cast<const short8*>(&B[(size_t)brow * K + kt + kl]);
      int off = srow * 128 + ((kl * 2) ^ ((srow & 7) << 4));
      *reinterpret_cast<short8*>(reinterpret_cast<char*>(Bs) + off) = v;
    }
    __syncthreads();
    #pragma unroll
    for (int kk = 0; kk < 64; kk += 32) {
      short8 af[4], bfr[4];
      const int kb = (kk + (l >> 4) * 8) * 2;
      #pragma unroll
      for (int mt = 0; mt < 4; ++mt) {
        int row = wr * 64 + mt * 16 + (l & 15);
        int off = row * 128 + (kb ^ ((row & 7) << 4));
        af[mt] = *reinterpret_cast<const short8*>(reinterpret_cast<const char*>(As) + off);
      }
      #pragma unroll
      for (int nt = 0; nt < 4; ++nt) {
        int row = wc * 64 + nt * 16 + (l & 15);
        int off = row * 128 + (kb ^ ((row & 7) << 4));
        bfr[nt] = *reinterpret_cast<const short8*>(reinterpret_cast<const char*>(Bs) + off);
      }
      #pragma unroll
      for (int mt = 0; mt < 4; ++mt)
        #pragma unroll
        for (int nt = 0; nt < 4; ++nt)
          acc[mt][nt] = __builtin_amdgcn_mfma_f32_16x16x32_bf16(af[mt], bfr[nt], acc[mt][nt], 0, 0, 0);
    }
    __syncthreads();
  }
  #pragma unroll
  for (int mt = 0; mt < 4; ++mt)
    #pragma unroll
    for (int nt = 0; nt < 4; ++nt)
      #pragma unroll
      for (int i = 0; i < 4; ++i) {
        int row = wr * 64 + mt * 16 + (l >> 4) * 4 + i;
        int col = wc * 64 + nt * 16 + (l & 15);
        int gr = gm0 + row, gc = gn0 + col;
        if (!GUARD_N || gc < N) {
          float v = acc[mt][nt][i] + (BIAS_ON_M ? bias[gr] : bias[gc]);
          if (CB16) ((bf16*)Cv)[(size_t)gr * N + gc] = __float2bfloat16(v);
          else      ((float*)Cv)[(size_t)gr * N + gc] = v;
        }
      }
}

// ---------------------------------------------------------------------------
// Tree-GRU recurrence. h(t) in HSTEP[t] (fresh buffer per step), layout
// [jb][d][8] bf16, PLAIN loads/stores. Barrier = R2's PROVEN protocol:
// per-WG tid0 RELEASE fetch_add -> spin -> ACQUIRE agent fence.
// ---------------------------------------------------------------------------
__global__ __launch_bounds__(256) void k_recur(const bf16* __restrict__ whhp,
                                               const bf16* __restrict__ giT,
                                               const float* __restrict__ bghn,
                                               const int* __restrict__ edges,
                                               float* __restrict__ hf,
                                               bf16* __restrict__ hsteps,
                                               bf16* __restrict__ outs,
                                               unsigned* __restrict__ bar) {
  __shared__ float lds_p[4][64][49];   // padded: conflict-free strided reads
  const int tid = threadIdx.x, l = tid & 63, w = tid >> 6;
  const int ms = blockIdx.x >> 1, dh = blockIdx.x & 1;
  const int kw = w * 128;

  // register-resident Whh slice: 48 rows x 128 k per wave (full K via 4-wave split)
  short8 areg[3][4];
  #pragma unroll
  for (int mt = 0; mt < 3; ++mt)
    #pragma unroll
    for (int ks = 0; ks < 4; ++ks) {
      int row = ms * 48 + mt * 16 + (l & 15);
      int k = kw + ks * 32 + (l >> 4) * 8;
      areg[mt][ks] = *reinterpret_cast<const short8*>(&whhp[(size_t)row * H_ + k]);
    }

  // epilogue ownership: thread -> (d = tid>>2, j-pair = (tid&3)*2)
  const int dl = tid >> 2;
  const int jp = (tid & 3) * 2;
  const int dg = dh * 64 + dl;
  const int jg0 = ms * 8 + jp;
  float bgh[12];
  #pragma unroll
  for (int q = 0; q < 12; ++q) bgh[q] = bghn[ms * 48 + jp * 6 + q];
  float hstate[2] = { hf[dg * H_ + jg0], hf[dg * H_ + jg0 + 1] };
  const bf16* gbase = giT + (size_t)(ms * 48 + jp * 6) * SD_ + dg;

  // prefetch step-0 gi + edge
  float gic[12]; int edc;
  #pragma unroll
  for (int q = 0; q < 12; ++q) gic[q] = __bfloat162float(gbase[(size_t)q * SD_]);
  edc = edges[dg];

  #pragma unroll 1
  for (int t = 0; t < S_; ++t) {
    // prefetch next step's gi + edge (independent of h; hides under MFMA)
    float gin[12]; int edn;
    if (t + 1 < S_) {
      #pragma unroll
      for (int q = 0; q < 12; ++q) gin[q] = __bfloat162float(gbase[(size_t)q * SD_ + (t + 1) * D_]);
      edn = edges[(t + 1) * D_ + dg];
    } else {
      edn = 0;
      #pragma unroll
      for (int q = 0; q < 12; ++q) gin[q] = 0.f;
    }

    const bf16* hb = hsteps + (size_t)t * (D_ * H_);
    bf16* hnb = hsteps + (size_t)(t + 1) * (D_ * H_);

    // issue all 16 b-fragment loads (plain; compiler handles waitcnt)
    short8 bfr[4][4];
    #pragma unroll
    for (int ks = 0; ks < 4; ++ks)
      #pragma unroll
      for (int nt = 0; nt < 4; ++nt) {
        int jb = w * 16 + ks * 4 + (l >> 4);
        int d = dh * 64 + nt * 16 + (l & 15);
        bfr[ks][nt] = *reinterpret_cast<const short8*>(hb + ((size_t)jb * D_ + d) * 8);
      }

    f32x4 acc[3][4];
    #pragma unroll
    for (int a = 0; a < 3; ++a)
      #pragma unroll
      for (int b = 0; b < 4; ++b) acc[a][b] = zero4();
    #pragma unroll
    for (int ks = 0; ks < 4; ++ks)
      #pragma unroll
      for (int mt = 0; mt < 3; ++mt)
        #pragma unroll
        for (int nt = 0; nt < 4; ++nt)
          acc[mt][nt] = __builtin_amdgcn_mfma_f32_16x16x32_bf16(areg[mt][ks], bfr[ks][nt], acc[mt][nt], 0, 0, 0);

    __syncthreads();   // prior-iteration epilogue reads of lds_p complete
    #pragma unroll
    for (int mt = 0; mt < 3; ++mt)
      #pragma unroll
      for (int nt = 0; nt < 4; ++nt) {
        int col = nt * 16 + (l & 15);
        int r0 = mt * 16 + (l >> 4) * 4;
        #pragma unroll
        for (int i = 0; i < 4; ++i) lds_p[w][col][r0 + i] = acc[mt][nt][i];
      }
    __syncthreads();

    // epilogue: 2 adjacent j's of one d-row per thread
    unsigned hpack;
    #pragma unroll
    for (int sl = 0; sl < 2; ++sl) {
      float gh[6];
      #pragma unroll
      for (int q = 0; q < 6; ++q) {
        int r = (jp + sl) * 6 + q;
        gh[q] = lds_p[0][dl][r] + lds_p[1][dl][r] + lds_p[2][dl][r]
              + lds_p[3][dl][r] + bgh[sl * 6 + q];
      }
      float rc = sigm(gic[sl * 6 + 0] + gh[0]);
      float zc = sigm(gic[sl * 6 + 1] + gh[1]);
      float nc = tanhf(gic[sl * 6 + 2] + rc * gh[2]);
      float rs = sigm(gic[sl * 6 + 3] + gh[3]);
      float zs = sigm(gic[sl * 6 + 4] + gh[4]);
      float ns = tanhf(gic[sl * 6 + 5] + rs * gh[5]);
      float ho = hstate[sl];
      float hc = (1.f - zc) * nc + zc * ho;
      float hs = (1.f - zs) * ns + zs * ho;
      float hv = (edc != 0) ? hc : hs;
      hstate[sl] = hv;
      bf16 hvb = __float2bfloat16(hv);
      reinterpret_cast<unsigned short*>(&hpack)[sl] = *reinterpret_cast<unsigned short*>(&hvb);
    }
    // h-next: contiguous 1KB per WG (plain store)
    *reinterpret_cast<unsigned*>(hnb + ((size_t)ms * D_ + dg) * 8 + jp) = hpack;
    if (outs) {
      *reinterpret_cast<unsigned*>(&outs[(size_t)t * (D_ * H_) + dg * H_ + jg0]) = hpack;
    }
    // rotate prefetch
    edc = edn;
    #pragma unroll
    for (int q = 0; q < 12; ++q) gic[q] = gin[q];

    if (t + 1 < S_) {
      __syncthreads();   // all WG stores drained (compiler emits vmcnt(0) at barrier)
      if (tid == 0) {
        unsigned* c = bar + t * 2 + dh;
        __hip_atomic_fetch_add(c, 1u, __ATOMIC_RELEASE, __HIP_MEMORY_SCOPE_AGENT);
        while (__hip_atomic_load(c, __ATOMIC_RELAXED, __HIP_MEMORY_SCOPE_AGENT) < NWG_HALF)
          __builtin_amdgcn_s_sleep(2);
        __builtin_amdgcn_fence(__ATOMIC_ACQUIRE, "agent");
      }
      __syncthreads();
    }
  }
  hf[dg * H_ + jg0]     = hstate[0];
  hf[dg * H_ + jg0 + 1] = hstate[1];
}

// mean/logv/z from final encoder h (f32)
__global__ __launch_bounds__(256) void k_latent(const float* __restrict__ hf,
    const float* __restrict__ h2mW, const float* __restrict__ h2mB,
    const float* __restrict__ h2lW, const float* __restrict__ h2lB,
    const float* __restrict__ eps, float* __restrict__ om, float* __restrict__ ov,
    float* __restrict__ oz, float* __restrict__ zf) {
  __shared__ float hrow[H_];
  const int d = blockIdx.x;
  for (int k = threadIdx.x; k < H_; k += 256) hrow[k] = hf[d * H_ + k];
  __syncthreads();
  const int lc = threadIdx.x;   // L_ == 256
  const float* wm = &h2mW[(size_t)lc * H_];
  const float* wl = &h2lW[(size_t)lc * H_];
  float m = 0.f, v = 0.f;
  for (int k = 0; k < H_; ++k) { float h = hrow[k]; m += h * wm[k]; v += h * wl[k]; }
  m += h2mB[lc]; v += h2lB[lc];
  float z = eps[d * L_ + lc] * __expf(0.5f * v) + m;
  om[d * L_ + lc] = m; ov[d * L_ + lc] = v; oz[d * L_ + lc] = z; zf[d * L_ + lc] = z;
}

__global__ __launch_bounds__(256) void k_decinit(const float* __restrict__ zf,
    const float* __restrict__ l2hW, const float* __restrict__ l2hB,
    float* __restrict__ hf, bf16* __restrict__ hx0) {
  __shared__ float zrow[L_];
  const int d = blockIdx.x;
  if (threadIdx.x < L_) zrow[threadIdx.x] = zf[d * L_ + threadIdx.x];
  __syncthreads();
  for (int j = threadIdx.x; j < H_; j += 256) {
    const float* wr = &l2hW[(size_t)j * L_];
    float a = 0.f;
    for (int k = 0; k < L_; ++k) a += zrow[k] * wr[k];
    a += l2hB[j];
    hf[d * H_ + j] = a;
    hx0[((j >> 3) * D_ + d) * 8 + (j & 7)] = __float2bfloat16(a);
  }
}

__global__ __launch_bounds__(256) void k_logsoftmax(float* __restrict__ lg) {
  __shared__ float buf[V_];
  __shared__ float redm[4], reds[4];
  const size_t base = (size_t)blockIdx.x * V_;
  const int tid = threadIdx.x;
  float lmax = -3.0e38f;
  for (int i = tid; i < V_; i += 256) { float x = lg[base + i]; buf[i] = x; lmax = fmaxf(lmax, x); }
  #pragma unroll
  for (int off = 32; off > 0; off >>= 1) lmax = fmaxf(lmax, __shfl_down(lmax, off, 64));
  if ((tid & 63) == 0) redm[tid >> 6] = lmax;
  __syncthreads();
  const float gmax = fmaxf(fmaxf(redm[0], redm[1]), fmaxf(redm[2], redm[3]));
  float s = 0.f;
  for (int i = tid; i < V_; i += 256) s += __expf(buf[i] - gmax);
  #pragma unroll
  for (int off = 32; off > 0; off >>= 1) s += __shfl_down(s, off, 64);
  if ((tid & 63) == 0) reds[tid >> 6] = s;
  __syncthreads();
  const float lse = gmax + __logf(reds[0] + reds[1] + reds[2] + reds[3]);
  for (int i = tid; i < V_; i += 256) lg[base + i] = buf[i] - lse;
}

// ---------------------------------------------------------------------------
extern "C" void kernel_launch(void* const* d_in, const int* in_sizes, int n_in,
                              void* d_out, int out_size, void* d_ws, size_t ws_size,
                              hipStream_t stream) {
  const int* nodes = (const int*)d_in[0];
  const int* edges = (const int*)d_in[1];
  const float* emb = (const float*)d_in[2];
  PrepArgs pa;
  for (int c = 0; c < 4; ++c) {
    pa.wih[c] = (const float*)d_in[3 + c * 4 + 0];
    pa.whh[c] = (const float*)d_in[3 + c * 4 + 1];
    pa.bih[c] = (const float*)d_in[3 + c * 4 + 2];
    pa.bhh[c] = (const float*)d_in[3 + c * 4 + 3];
  }
  const float* h2mW = (const float*)d_in[19];
  const float* h2mB = (const float*)d_in[20];
  const float* h2lW = (const float*)d_in[21];
  const float* h2lB = (const float*)d_in[22];
  const float* l2hW = (const float*)d_in[23];
  const float* l2hB = (const float*)d_in[24];
  const float* o2vW = (const float*)d_in[25];
  const float* o2vB = (const float*)d_in[26];
  const float* enc_init = (const float*)d_in[27];
  const float* eps = (const float*)d_in[28];

  char* ws = (char*)d_ws;
  size_t off = 0;
  bf16* WIHP = (bf16*)(ws + off); off += (size_t)2 * M3_ * H_ * 2;
  bf16* WHHP = (bf16*)(ws + off); off += (size_t)2 * M3_ * H_ * 2;
  float* BGI  = (float*)(ws + off); off += (size_t)2 * M3_ * 4;
  float* BGHN = (float*)(ws + off); off += (size_t)2 * M3_ * 4;
  bf16* XB   = (bf16*)(ws + off); off += (size_t)SD_ * H_ * 2;
  bf16* O2VB = (bf16*)(ws + off); off += (size_t)V_ * H_ * 2;
  float* HF  = (float*)(ws + off); off += (size_t)D_ * H_ * 4;
  bf16* HSTEPE = (bf16*)(ws + off); off += (size_t)(S_ + 1) * D_ * H_ * 2;  // 6.4 MB
  bf16* HSTEPD = (bf16*)(ws + off); off += (size_t)(S_ + 1) * D_ * H_ * 2;  // 6.4 MB
  float* ZF  = (float*)(ws + off); off += (size_t)D_ * L_ * 4;
  bf16* OUTS = (bf16*)(ws + off); off += (size_t)S_ * D_ * H_ * 2;
  bf16* GITB = (bf16*)(ws + off); off += (size_t)M3_ * SD_ * 2;             // 37.7 MB
  unsigned* BAR = (unsigned*)(ws + off); off += 2 * S_ * 2 * sizeof(unsigned);
  (void)ws_size; (void)in_sizes; (void)n_in; (void)out_size;

  float* out_logp = (float*)d_out;
  float* out_mean = out_logp + (size_t)SD_ * V_;
  float* out_logv = out_mean + (size_t)D_ * L_;
  float* out_z    = out_logv + (size_t)D_ * L_;

  // zero barrier counters every call (ws not re-poisoned between replays)
  hipMemsetAsync(BAR, 0, 2 * S_ * 2 * sizeof(unsigned), stream);

  // prep
  hipLaunchKernelGGL(k_prep_w, dim3(2 * M3_), dim3(64), 0, stream, pa, WIHP, WHHP, BGI, BGHN);
  hipLaunchKernelGGL(k_gather_x, dim3((SD_ * H_ + 255) / 256), dim3(256), 0, stream, nodes, emb, XB);
  hipLaunchKernelGGL(k_cvt_bf16, dim3((V_ * H_ + 255) / 256), dim3(256), 0, stream, o2vW, O2VB, V_ * H_);
  hipLaunchKernelGGL(k_init_h, dim3((D_ * H_ + 255) / 256), dim3(256), 0, stream, enc_init, HF, HSTEPE);

  // encoder: gi GEMM (bf16 out) + recurrence
  hipLaunchKernelGGL((k_gemm<true, false, true>), dim3(SD_ / 128, M3_ / 128), dim3(256), 0, stream,
                     WIHP, XB, BGI, (void*)GITB, M3_, SD_);
  {
    const bf16* whhpE = WHHP; const bf16* gitp = GITB; const float* bghnE = BGHN;
    float* hfp = HF; bf16* hstep = HSTEPE; bf16* outs0 = nullptr;
    const int* edg = edges; unsigned* barE = BAR;
    void* args[] = {(void*)&whhpE, (void*)&gitp, (void*)&bghnE, (void*)&edg,
                    (void*)&hfp, (void*)&hstep, (void*)&outs0, (void*)&barE};
    hipLaunchCooperativeKernel((const void*)k_recur, dim3(128), dim3(256), args, 0, stream);
  }

  hipLaunchKernelGGL(k_latent, dim3(D_), dim3(256), 0, stream, HF, h2mW, h2mB, h2lW, h2lB,
                     eps, out_mean, out_logv, out_z, ZF);
  hipLaunchKernelGGL(k_decinit, dim3(D_), dim3(256), 0, stream, ZF, l2hW, l2hB, HF, HSTEPD);

  // decoder: gi GEMM + recurrence (writes OUTS)
  hipLaunchKernelGGL((k_gemm<true, false, true>), dim3(SD_ / 128, M3_ / 128), dim3(256), 0, stream,
                     WIHP + (size_t)M3_ * H_, XB, BGI + M3_, (void*)GITB, M3_, SD_);
  {
    const bf16* whhpD = WHHP + (size_t)M3_ * H_; const bf16* gitp = GITB;
    const float* bghnD = BGHN + M3_;
    float* hfp = HF; bf16* hstep = HSTEPD; bf16* outsP = OUTS;
    const int* edg = edges; unsigned* barD = BAR + S_ * 2;
    void* args[] = {(void*)&whhpD, (void*)&gitp, (void*)&bghnD, (void*)&edg,
                    (void*)&hfp, (void*)&hstep, (void*)&outsP, (void*)&barD};
    hipLaunchCooperativeKernel((const void*)k_recur, dim3(128), dim3(256), args, 0, stream);
  }

  // logits + log_softmax (in-place in d_out)
  hipLaunchKernelGGL((k_gemm<false, true, false>), dim3((V_ + 127) / 128, SD_ / 128), dim3(256), 0, stream,
                     OUTS, O2VB, o2vB, (void*)out_logp, SD_, V_);
  hipLaunchKernelGGL(k_logsoftmax, dim3(SD_), dim3(256), 0, stream, out_logp);
}

// Round 7
// 812.999 us; speedup vs baseline: 5.5084x; 1.2526x over previous
//
#include <hip/hip_runtime.h>
#include <hip/hip_bf16.h>

#define S_ 48
#define D_ 128
#define H_ 512
#define L_ 256
#define V_ 6000
#define SD_ 6144      // S*D
#define M3_ 3072      // 6*H permuted gate rows per tree
#define NWG_HALF 64   // WGs per dh-half barrier group

// barrier region layout (unsigned words), one region per recurrence dispatch
#define SB_ (S_ - 1)          // 47 in-kernel barriers
#define REGC_OFF 0            // [2][8]  per (dh, xcd) WG count
#define SETUP_OFF 16          // [2]     setup barrier
#define XARR_OFF 18           // [2][8][SB_] per-step per-XCD arrivals
#define GREADY_OFF (18 + 2*8*SB_)            // [2][SB_] flushed-XCD count
#define INVD_OFF (18 + 2*8*SB_ + 2*SB_)      // [2][8][SB_] inv-done flags
#define BAR_WORDS (18 + 2*8*SB_ + 2*SB_ + 2*8*SB_)

typedef __attribute__((ext_vector_type(8))) short short8;
typedef __attribute__((ext_vector_type(4))) float f32x4;
typedef __hip_bfloat16 bf16;

__device__ __forceinline__ float sigm(float x) { return 1.0f / (1.0f + __expf(-x)); }
__device__ __forceinline__ f32x4 zero4() { f32x4 z; z[0]=0.f; z[1]=0.f; z[2]=0.f; z[3]=0.f; return z; }

// ---------------------------------------------------------------------------
// Prep kernels
// ---------------------------------------------------------------------------
struct PrepArgs {
  const float* wih[4]; const float* whh[4];
  const float* bih[4]; const float* bhh[4];
};

__global__ __launch_bounds__(64) void k_prep_w(PrepArgs pa, bf16* __restrict__ wihp,
                                               bf16* __restrict__ whhp,
                                               float* __restrict__ bgi,
                                               float* __restrict__ bghn) {
  const int R = blockIdx.x;
  const int tree = R / M3_;
  const int p = R - tree * M3_;
  const int j = p / 6;
  const int t6 = p - j * 6;
  const int sib = (t6 >= 3) ? 1 : 0;
  const int g = t6 - sib * 3;
  const int cell = tree * 2 + sib;
  const int srow = g * H_ + j;
  const float* wi = pa.wih[cell] + (size_t)srow * H_;
  const float* wh = pa.whh[cell] + (size_t)srow * H_;
  bf16* di = wihp + (size_t)R * H_;
  bf16* dh = whhp + (size_t)R * H_;
  const int k0 = threadIdx.x * 8;
  #pragma unroll
  for (int i = 0; i < 8; ++i) {
    di[k0 + i] = __float2bfloat16(wi[k0 + i]);
    dh[k0 + i] = __float2bfloat16(wh[k0 + i]);
  }
  if (threadIdx.x == 0) {
    float bi = pa.bih[cell][srow], bh = pa.bhh[cell][srow];
    bgi[R]  = bi + (g < 2 ? bh : 0.f);
    bghn[R] = (g == 2 ? bh : 0.f);
  }
}

__global__ void k_gather_x(const int* __restrict__ nodes, const float* __restrict__ emb,
                           bf16* __restrict__ X) {
  int i = blockIdx.x * 256 + threadIdx.x;
  if (i < SD_ * H_) {
    int sd = i >> 9, k = i & 511;
    X[i] = __float2bfloat16(emb[(size_t)nodes[sd] * H_ + k]);
  }
}

__global__ void k_cvt_bf16(const float* __restrict__ src, bf16* __restrict__ dst, int n) {
  int i = blockIdx.x * 256 + threadIdx.x;
  if (i < n) dst[i] = __float2bfloat16(src[i]);
}

// h(0): hf f32 [d][j]  +  HSTEPE[0] bf16 [jb][d][8]
__global__ void k_init_h(const float* __restrict__ init, float* __restrict__ hf,
                         bf16* __restrict__ hx0) {
  int i = blockIdx.x * 256 + threadIdx.x;
  if (i < D_ * H_) {
    int d = i >> 9, j = i & 511;
    float v = init[i];
    hf[i] = v;
    hx0[((j >> 3) * D_ + d) * 8 + (j & 7)] = __float2bfloat16(v);
  }
}

// ---------------------------------------------------------------------------
// Generic bf16 GEMM: C(M,N) = A(M,512) @ B(N,512)^T + bias; C f32 or bf16.
// ---------------------------------------------------------------------------
template<bool BIAS_ON_M, bool GUARD_N, bool CB16>
__global__ __launch_bounds__(256) void k_gemm(const bf16* __restrict__ A,
                                              const bf16* __restrict__ B,
                                              const float* __restrict__ bias,
                                              void* __restrict__ Cv, int M, int N) {
  constexpr int K = 512;
  __shared__ bf16 As[128 * 64];
  __shared__ bf16 Bs[128 * 64];
  const int tid = threadIdx.x;
  const int l = tid & 63, w = tid >> 6;
  const int gm0 = blockIdx.y * 128, gn0 = blockIdx.x * 128;
  const int wr = w >> 1, wc = w & 1;
  f32x4 acc[4][4];
  #pragma unroll
  for (int a = 0; a < 4; ++a)
    #pragma unroll
    for (int b = 0; b < 4; ++b) acc[a][b] = zero4();

  const int srow = tid >> 1;
  const int kc0 = (tid & 1) * 32;

  for (int kt = 0; kt < K; kt += 64) {
    #pragma unroll
    for (int c = 0; c < 4; ++c) {
      int kl = kc0 + c * 8;
      short8 v = *reinterpret_cast<const short8*>(&A[(size_t)(gm0 + srow) * K + kt + kl]);
      int off = srow * 128 + ((kl * 2) ^ ((srow & 7) << 4));
      *reinterpret_cast<short8*>(reinterpret_cast<char*>(As) + off) = v;
    }
    #pragma unroll
    for (int c = 0; c < 4; ++c) {
      int kl = kc0 + c * 8;
      int brow = gn0 + srow;
      if (GUARD_N) brow = brow < N ? brow : N - 1;
      short8 v = *reinterpret_cast<const short8*>(&B[(size_t)brow * K + kt + kl]);
      int off = srow * 128 + ((kl * 2) ^ ((srow & 7) << 4));
      *reinterpret_cast<short8*>(reinterpret_cast<char*>(Bs) + off) = v;
    }
    __syncthreads();
    #pragma unroll
    for (int kk = 0; kk < 64; kk += 32) {
      short8 af[4], bfr[4];
      const int kb = (kk + (l >> 4) * 8) * 2;
      #pragma unroll
      for (int mt = 0; mt < 4; ++mt) {
        int row = wr * 64 + mt * 16 + (l & 15);
        int off = row * 128 + (kb ^ ((row & 7) << 4));
        af[mt] = *reinterpret_cast<const short8*>(reinterpret_cast<const char*>(As) + off);
      }
      #pragma unroll
      for (int nt = 0; nt < 4; ++nt) {
        int row = wc * 64 + nt * 16 + (l & 15);
        int off = row * 128 + (kb ^ ((row & 7) << 4));
        bfr[nt] = *reinterpret_cast<const short8*>(reinterpret_cast<const char*>(Bs) + off);
      }
      #pragma unroll
      for (int mt = 0; mt < 4; ++mt)
        #pragma unroll
        for (int nt = 0; nt < 4; ++nt)
          acc[mt][nt] = __builtin_amdgcn_mfma_f32_16x16x32_bf16(af[mt], bfr[nt], acc[mt][nt], 0, 0, 0);
    }
    __syncthreads();
  }
  #pragma unroll
  for (int mt = 0; mt < 4; ++mt)
    #pragma unroll
    for (int nt = 0; nt < 4; ++nt)
      #pragma unroll
      for (int i = 0; i < 4; ++i) {
        int row = wr * 64 + mt * 16 + (l >> 4) * 4 + i;
        int col = wc * 64 + nt * 16 + (l & 15);
        int gr = gm0 + row, gc = gn0 + col;
        if (!GUARD_N || gc < N) {
          float v = acc[mt][nt][i] + (BIAS_ON_M ? bias[gr] : bias[gc]);
          if (CB16) ((bf16*)Cv)[(size_t)gr * N + gc] = __float2bfloat16(v);
          else      ((float*)Cv)[(size_t)gr * N + gc] = v;
        }
      }
}

// ---------------------------------------------------------------------------
// Tree-GRU recurrence. h(t) in HSTEP[t] (fresh buffer per step), [jb][d][8]
// bf16, plain loads/stores. Barrier: per-XCD designated WG (via XCC_ID)
// performs the single RELEASE wbl2 and ACQUIRE inv for its whole XCD;
// all other WGs use RELAXED arrivals + a free workgroup-scope fence.
// ---------------------------------------------------------------------------
__global__ __launch_bounds__(256) void k_recur(const bf16* __restrict__ whhp,
                                               const bf16* __restrict__ giT,
                                               const float* __restrict__ bghn,
                                               const int* __restrict__ edges,
                                               float* __restrict__ hf,
                                               bf16* __restrict__ hsteps,
                                               bf16* __restrict__ outs,
                                               unsigned* __restrict__ bar) {
  __shared__ float lds_p[4][64][52];   // 52-pad: 16B-aligned f32x4, 2-way banks (free)
  const int tid = threadIdx.x, l = tid & 63, w = tid >> 6;
  const int ms = blockIdx.x >> 1, dh = blockIdx.x & 1;
  const int kw = w * 128;

  // ---- registration: count WGs per (dh, XCD); first registrant = designate
  unsigned my_xcc = 0, my_desig = 0, my_xcdcnt = 0, my_nxcd = 0;
  if (tid == 0) {
    asm volatile("s_getreg_b32 %0, hwreg(HW_REG_XCC_ID)" : "=s"(my_xcc));
    my_xcc &= 7;
    unsigned prev = __hip_atomic_fetch_add(bar + REGC_OFF + dh * 8 + my_xcc, 1u,
                                           __ATOMIC_RELAXED, __HIP_MEMORY_SCOPE_AGENT);
    my_desig = (prev == 0);
    unsigned* sb = bar + SETUP_OFF + dh;
    __hip_atomic_fetch_add(sb, 1u, __ATOMIC_RELEASE, __HIP_MEMORY_SCOPE_AGENT);
    while (__hip_atomic_load(sb, __ATOMIC_RELAXED, __HIP_MEMORY_SCOPE_AGENT) < NWG_HALF)
      __builtin_amdgcn_s_sleep(2);
    __builtin_amdgcn_fence(__ATOMIC_ACQUIRE, "agent");
    my_xcdcnt = __hip_atomic_load(bar + REGC_OFF + dh * 8 + my_xcc,
                                  __ATOMIC_RELAXED, __HIP_MEMORY_SCOPE_AGENT);
    #pragma unroll
    for (int x = 0; x < 8; ++x)
      my_nxcd += (__hip_atomic_load(bar + REGC_OFF + dh * 8 + x,
                                    __ATOMIC_RELAXED, __HIP_MEMORY_SCOPE_AGENT) > 0u) ? 1u : 0u;
  }

  // register-resident Whh slice: 48 rows x 128 k per wave (full K via 4-wave split)
  short8 areg[3][4];
  #pragma unroll
  for (int mt = 0; mt < 3; ++mt)
    #pragma unroll
    for (int ks = 0; ks < 4; ++ks) {
      int row = ms * 48 + mt * 16 + (l & 15);
      int k = kw + ks * 32 + (l >> 4) * 8;
      areg[mt][ks] = *reinterpret_cast<const short8*>(&whhp[(size_t)row * H_ + k]);
    }

  // epilogue ownership: thread -> (d = tid>>2, j-pair = (tid&3)*2)
  const int dl = tid >> 2;
  const int jp = (tid & 3) * 2;
  const int dg = dh * 64 + dl;
  const int jg0 = ms * 8 + jp;
  float bgh[12];
  #pragma unroll
  for (int q = 0; q < 12; ++q) bgh[q] = bghn[ms * 48 + jp * 6 + q];
  float hstate[2] = { hf[dg * H_ + jg0], hf[dg * H_ + jg0 + 1] };
  const bf16* gbase = giT + (size_t)(ms * 48 + jp * 6) * SD_ + dg;

  // prefetch step-0 gi + edge
  float gic[12]; int edc;
  #pragma unroll
  for (int q = 0; q < 12; ++q) gic[q] = __bfloat162float(gbase[(size_t)q * SD_]);
  edc = edges[dg];

  #pragma unroll 1
  for (int t = 0; t < S_; ++t) {
    // prefetch next step's gi + edge (independent of h; hides under MFMA)
    float gin[12]; int edn;
    if (t + 1 < S_) {
      #pragma unroll
      for (int q = 0; q < 12; ++q) gin[q] = __bfloat162float(gbase[(size_t)q * SD_ + (t + 1) * D_]);
      edn = edges[(t + 1) * D_ + dg];
    } else {
      edn = 0;
      #pragma unroll
      for (int q = 0; q < 12; ++q) gin[q] = 0.f;
    }

    const bf16* hb = hsteps + (size_t)t * (D_ * H_);
    bf16* hnb = hsteps + (size_t)(t + 1) * (D_ * H_);

    // issue all 16 b-fragment loads (plain; compiler handles waitcnt)
    short8 bfr[4][4];
    #pragma unroll
    for (int ks = 0; ks < 4; ++ks)
      #pragma unroll
      for (int nt = 0; nt < 4; ++nt) {
        int jb = w * 16 + ks * 4 + (l >> 4);
        int d = dh * 64 + nt * 16 + (l & 15);
        bfr[ks][nt] = *reinterpret_cast<const short8*>(hb + ((size_t)jb * D_ + d) * 8);
      }

    f32x4 acc[3][4];
    #pragma unroll
    for (int a = 0; a < 3; ++a)
      #pragma unroll
      for (int b = 0; b < 4; ++b) acc[a][b] = zero4();
    #pragma unroll
    for (int ks = 0; ks < 4; ++ks)
      #pragma unroll
      for (int mt = 0; mt < 3; ++mt)
        #pragma unroll
        for (int nt = 0; nt < 4; ++nt)
          acc[mt][nt] = __builtin_amdgcn_mfma_f32_16x16x32_bf16(areg[mt][ks], bfr[ks][nt], acc[mt][nt], 0, 0, 0);

    __syncthreads();   // prior-iteration epilogue reads of lds_p complete
    #pragma unroll
    for (int mt = 0; mt < 3; ++mt)
      #pragma unroll
      for (int nt = 0; nt < 4; ++nt) {
        int col = nt * 16 + (l & 15);
        int r0 = mt * 16 + (l >> 4) * 4;
        *reinterpret_cast<f32x4*>(&lds_p[w][col][r0]) = acc[mt][nt];
      }
    __syncthreads();

    // epilogue: 2 adjacent j's of one d-row per thread
    unsigned hpack;
    #pragma unroll
    for (int sl = 0; sl < 2; ++sl) {
      float gh[6];
      #pragma unroll
      for (int q = 0; q < 6; ++q) {
        int r = (jp + sl) * 6 + q;
        gh[q] = lds_p[0][dl][r] + lds_p[1][dl][r] + lds_p[2][dl][r]
              + lds_p[3][dl][r] + bgh[sl * 6 + q];
      }
      float rc = sigm(gic[sl * 6 + 0] + gh[0]);
      float zc = sigm(gic[sl * 6 + 1] + gh[1]);
      float nc = tanhf(gic[sl * 6 + 2] + rc * gh[2]);
      float rs = sigm(gic[sl * 6 + 3] + gh[3]);
      float zs = sigm(gic[sl * 6 + 4] + gh[4]);
      float ns = tanhf(gic[sl * 6 + 5] + rs * gh[5]);
      float ho = hstate[sl];
      float hc = (1.f - zc) * nc + zc * ho;
      float hs = (1.f - zs) * ns + zs * ho;
      float hv = (edc != 0) ? hc : hs;
      hstate[sl] = hv;
      bf16 hvb = __float2bfloat16(hv);
      reinterpret_cast<unsigned short*>(&hpack)[sl] = *reinterpret_cast<unsigned short*>(&hvb);
    }
    // h-next: contiguous 1KB per WG (plain store; write-through L1 -> L2)
    *reinterpret_cast<unsigned*>(hnb + ((size_t)ms * D_ + dg) * 8 + jp) = hpack;
    if (outs) {
      *reinterpret_cast<unsigned*>(&outs[(size_t)t * (D_ * H_) + dg * H_ + jg0]) = hpack;
    }
    // rotate prefetch
    edc = edn;
    #pragma unroll
    for (int q = 0; q < 12; ++q) gic[q] = gin[q];

    if (t + 1 < S_) {
      __syncthreads();   // all WG stores drained to L2 (vmcnt(0) at barrier)
      if (tid == 0) {
        unsigned* xa = bar + XARR_OFF + ((dh * 8 + my_xcc) * SB_ + t);
        unsigned* gr = bar + GREADY_OFF + (dh * SB_ + t);
        unsigned* id = bar + INVD_OFF + ((dh * 8 + my_xcc) * SB_ + t);
        __hip_atomic_fetch_add(xa, 1u, __ATOMIC_RELAXED, __HIP_MEMORY_SCOPE_AGENT);
        if (my_desig) {
          while (__hip_atomic_load(xa, __ATOMIC_RELAXED, __HIP_MEMORY_SCOPE_AGENT) < my_xcdcnt)
            __builtin_amdgcn_s_sleep(1);
          // ONE release (wbl2: flush this XCD's dirty h lines) per XCD per step
          __hip_atomic_fetch_add(gr, 1u, __ATOMIC_RELEASE, __HIP_MEMORY_SCOPE_AGENT);
          while (__hip_atomic_load(gr, __ATOMIC_RELAXED, __HIP_MEMORY_SCOPE_AGENT) < my_nxcd)
            __builtin_amdgcn_s_sleep(1);
          // ONE acquire (inv: invalidate this XCD's L2) per XCD per step
          __builtin_amdgcn_fence(__ATOMIC_ACQUIRE, "agent");
          __hip_atomic_fetch_add(id, 1u, __ATOMIC_RELAXED, __HIP_MEMORY_SCOPE_AGENT);
        } else {
          while (__hip_atomic_load(id, __ATOMIC_RELAXED, __HIP_MEMORY_SCOPE_AGENT) < 1u)
            __builtin_amdgcn_s_sleep(1);
          __builtin_amdgcn_fence(__ATOMIC_ACQUIRE, "workgroup");  // compile-order only, no cache ops
        }
      }
      __syncthreads();
    }
  }
  hf[dg * H_ + jg0]     = hstate[0];
  hf[dg * H_ + jg0 + 1] = hstate[1];
}

// mean/logv/z from final encoder h (f32)
__global__ __launch_bounds__(256) void k_latent(const float* __restrict__ hf,
    const float* __restrict__ h2mW, const float* __restrict__ h2mB,
    const float* __restrict__ h2lW, const float* __restrict__ h2lB,
    const float* __restrict__ eps, float* __restrict__ om, float* __restrict__ ov,
    float* __restrict__ oz, float* __restrict__ zf) {
  __shared__ float hrow[H_];
  const int d = blockIdx.x;
  for (int k = threadIdx.x; k < H_; k += 256) hrow[k] = hf[d * H_ + k];
  __syncthreads();
  const int lc = threadIdx.x;   // L_ == 256
  const float* wm = &h2mW[(size_t)lc * H_];
  const float* wl = &h2lW[(size_t)lc * H_];
  float m = 0.f, v = 0.f;
  for (int k = 0; k < H_; ++k) { float h = hrow[k]; m += h * wm[k]; v += h * wl[k]; }
  m += h2mB[lc]; v += h2lB[lc];
  float z = eps[d * L_ + lc] * __expf(0.5f * v) + m;
  om[d * L_ + lc] = m; ov[d * L_ + lc] = v; oz[d * L_ + lc] = z; zf[d * L_ + lc] = z;
}

__global__ __launch_bounds__(256) void k_decinit(const float* __restrict__ zf,
    const float* __restrict__ l2hW, const float* __restrict__ l2hB,
    float* __restrict__ hf, bf16* __restrict__ hx0) {
  __shared__ float zrow[L_];
  const int d = blockIdx.x;
  if (threadIdx.x < L_) zrow[threadIdx.x] = zf[d * L_ + threadIdx.x];
  __syncthreads();
  for (int j = threadIdx.x; j < H_; j += 256) {
    const float* wr = &l2hW[(size_t)j * L_];
    float a = 0.f;
    for (int k = 0; k < L_; ++k) a += zrow[k] * wr[k];
    a += l2hB[j];
    hf[d * H_ + j] = a;
    hx0[((j >> 3) * D_ + d) * 8 + (j & 7)] = __float2bfloat16(a);
  }
}

__global__ __launch_bounds__(256) void k_logsoftmax(float* __restrict__ lg) {
  __shared__ float buf[V_];
  __shared__ float redm[4], reds[4];
  const size_t base = (size_t)blockIdx.x * V_;
  const int tid = threadIdx.x;
  float lmax = -3.0e38f;
  for (int i = tid; i < V_; i += 256) { float x = lg[base + i]; buf[i] = x; lmax = fmaxf(lmax, x); }
  #pragma unroll
  for (int off = 32; off > 0; off >>= 1) lmax = fmaxf(lmax, __shfl_down(lmax, off, 64));
  if ((tid & 63) == 0) redm[tid >> 6] = lmax;
  __syncthreads();
  const float gmax = fmaxf(fmaxf(redm[0], redm[1]), fmaxf(redm[2], redm[3]));
  float s = 0.f;
  for (int i = tid; i < V_; i += 256) s += __expf(buf[i] - gmax);
  #pragma unroll
  for (int off = 32; off > 0; off >>= 1) s += __shfl_down(s, off, 64);
  if ((tid & 63) == 0) reds[tid >> 6] = s;
  __syncthreads();
  const float lse = gmax + __logf(reds[0] + reds[1] + reds[2] + reds[3]);
  for (int i = tid; i < V_; i += 256) lg[base + i] = buf[i] - lse;
}

// ---------------------------------------------------------------------------
extern "C" void kernel_launch(void* const* d_in, const int* in_sizes, int n_in,
                              void* d_out, int out_size, void* d_ws, size_t ws_size,
                              hipStream_t stream) {
  const int* nodes = (const int*)d_in[0];
  const int* edges = (const int*)d_in[1];
  const float* emb = (const float*)d_in[2];
  PrepArgs pa;
  for (int c = 0; c < 4; ++c) {
    pa.wih[c] = (const float*)d_in[3 + c * 4 + 0];
    pa.whh[c] = (const float*)d_in[3 + c * 4 + 1];
    pa.bih[c] = (const float*)d_in[3 + c * 4 + 2];
    pa.bhh[c] = (const float*)d_in[3 + c * 4 + 3];
  }
  const float* h2mW = (const float*)d_in[19];
  const float* h2mB = (const float*)d_in[20];
  const float* h2lW = (const float*)d_in[21];
  const float* h2lB = (const float*)d_in[22];
  const float* l2hW = (const float*)d_in[23];
  const float* l2hB = (const float*)d_in[24];
  const float* o2vW = (const float*)d_in[25];
  const float* o2vB = (const float*)d_in[26];
  const float* enc_init = (const float*)d_in[27];
  const float* eps = (const float*)d_in[28];

  char* ws = (char*)d_ws;
  size_t off = 0;
  bf16* WIHP = (bf16*)(ws + off); off += (size_t)2 * M3_ * H_ * 2;
  bf16* WHHP = (bf16*)(ws + off); off += (size_t)2 * M3_ * H_ * 2;
  float* BGI  = (float*)(ws + off); off += (size_t)2 * M3_ * 4;
  float* BGHN = (float*)(ws + off); off += (size_t)2 * M3_ * 4;
  bf16* XB   = (bf16*)(ws + off); off += (size_t)SD_ * H_ * 2;
  bf16* O2VB = (bf16*)(ws + off); off += (size_t)V_ * H_ * 2;
  float* HF  = (float*)(ws + off); off += (size_t)D_ * H_ * 4;
  bf16* HSTEPE = (bf16*)(ws + off); off += (size_t)(S_ + 1) * D_ * H_ * 2;  // 6.4 MB
  bf16* HSTEPD = (bf16*)(ws + off); off += (size_t)(S_ + 1) * D_ * H_ * 2;  // 6.4 MB
  float* ZF  = (float*)(ws + off); off += (size_t)D_ * L_ * 4;
  bf16* OUTS = (bf16*)(ws + off); off += (size_t)S_ * D_ * H_ * 2;
  bf16* GITB = (bf16*)(ws + off); off += (size_t)M3_ * SD_ * 2;             // 37.7 MB
  unsigned* BAR = (unsigned*)(ws + off); off += 2 * BAR_WORDS * sizeof(unsigned);
  (void)ws_size; (void)in_sizes; (void)n_in; (void)out_size;

  float* out_logp = (float*)d_out;
  float* out_mean = out_logp + (size_t)SD_ * V_;
  float* out_logv = out_mean + (size_t)D_ * L_;
  float* out_z    = out_logv + (size_t)D_ * L_;

  // zero barrier counters every call (ws not re-poisoned between replays)
  hipMemsetAsync(BAR, 0, 2 * BAR_WORDS * sizeof(unsigned), stream);

  // prep
  hipLaunchKernelGGL(k_prep_w, dim3(2 * M3_), dim3(64), 0, stream, pa, WIHP, WHHP, BGI, BGHN);
  hipLaunchKernelGGL(k_gather_x, dim3((SD_ * H_ + 255) / 256), dim3(256), 0, stream, nodes, emb, XB);
  hipLaunchKernelGGL(k_cvt_bf16, dim3((V_ * H_ + 255) / 256), dim3(256), 0, stream, o2vW, O2VB, V_ * H_);
  hipLaunchKernelGGL(k_init_h, dim3((D_ * H_ + 255) / 256), dim3(256), 0, stream, enc_init, HF, HSTEPE);

  // encoder: gi GEMM (bf16 out) + recurrence
  hipLaunchKernelGGL((k_gemm<true, false, true>), dim3(SD_ / 128, M3_ / 128), dim3(256), 0, stream,
                     WIHP, XB, BGI, (void*)GITB, M3_, SD_);
  {
    const bf16* whhpE = WHHP; const bf16* gitp = GITB; const float* bghnE = BGHN;
    float* hfp = HF; bf16* hstep = HSTEPE; bf16* outs0 = nullptr;
    const int* edg = edges; unsigned* barE = BAR;
    void* args[] = {(void*)&whhpE, (void*)&gitp, (void*)&bghnE, (void*)&edg,
                    (void*)&hfp, (void*)&hstep, (void*)&outs0, (void*)&barE};
    hipLaunchCooperativeKernel((const void*)k_recur, dim3(128), dim3(256), args, 0, stream);
  }

  hipLaunchKernelGGL(k_latent, dim3(D_), dim3(256), 0, stream, HF, h2mW, h2mB, h2lW, h2lB,
                     eps, out_mean, out_logv, out_z, ZF);
  hipLaunchKernelGGL(k_decinit, dim3(D_), dim3(256), 0, stream, ZF, l2hW, l2hB, HF, HSTEPD);

  // decoder: gi GEMM + recurrence (writes OUTS)
  hipLaunchKernelGGL((k_gemm<true, false, true>), dim3(SD_ / 128, M3_ / 128), dim3(256), 0, stream,
                     WIHP + (size_t)M3_ * H_, XB, BGI + M3_, (void*)GITB, M3_, SD_);
  {
    const bf16* whhpD = WHHP + (size_t)M3_ * H_; const bf16* gitp = GITB;
    const float* bghnD = BGHN + M3_;
    float* hfp = HF; bf16* hstep = HSTEPD; bf16* outsP = OUTS;
    const int* edg = edges; unsigned* barD = BAR + BAR_WORDS;
    void* args[] = {(void*)&whhpD, (void*)&gitp, (void*)&bghnD, (void*)&edg,
                    (void*)&hfp, (void*)&hstep, (void*)&outsP, (void*)&barD};
    hipLaunchCooperativeKernel((const void*)k_recur, dim3(128), dim3(256), args, 0, stream);
  }

  // logits + log_softmax (in-place in d_out)
  hipLaunchKernelGGL((k_gemm<false, true, false>), dim3((V_ + 127) / 128, SD_ / 128), dim3(256), 0, stream,
                     OUTS, O2VB, o2vB, (void*)out_logp, SD_, V_);
  hipLaunchKernelGGL(k_logsoftmax, dim3(SD_), dim3(256), 0, stream, out_logp);
}